// Round 6
// baseline (1538.787 us; speedup 1.0000x reference)
//
#include <hip/hip_runtime.h>
#include <stdint.h>

typedef __bf16 bf16;
typedef __bf16 bf16x8 __attribute__((ext_vector_type(8)));
typedef __bf16 bf16x4 __attribute__((ext_vector_type(4)));
typedef __bf16 bf16x2 __attribute__((ext_vector_type(2)));
typedef float f32x4 __attribute__((ext_vector_type(4)));

static __device__ __forceinline__ float bflo(uint32_t u) { return __uint_as_float(u << 16); }
static __device__ __forceinline__ float bfhi(uint32_t u) { return __uint_as_float(u & 0xffff0000u); }

// ---------------- init ----------------

__global__ __launch_bounds__(256) void k_init(int* __restrict__ deg, float* __restrict__ stats,
                                              bf16* __restrict__ p, int* __restrict__ ssrc,
                                              int N, int NP, int Ecap) {
    int i = blockIdx.x * 256 + threadIdx.x;
    if (i < N) deg[i] = 0;
    if (i < 3 * 512) stats[i] = 0.f;
    if (i < Ecap) ssrc[i] = N;  // pad -> zero row
    if (i < 128) {
        int g = i >> 4, c = i & 15;
        p[(size_t)g * NP * 16 + (size_t)N * 16 + c] = (bf16)0.f;
    }
}

__global__ __launch_bounds__(256) void k_cvt_w(const float* __restrict__ wl, const float* __restrict__ wr,
                                               bf16* __restrict__ dst, int n) {
    int i = blockIdx.x * 256 + threadIdx.x;
    if (i >= n) return;
    dst[i] = (bf16)wl[i];
    dst[n + i] = (bf16)wr[i];
}

// ---------------- CSR build (XCD-sharded by dst range) ----------------

__global__ __launch_bounds__(256) void k_count(const int* __restrict__ dst, int* __restrict__ deg,
                                               int E, int B) {
    int g = blockIdx.x & 7;
    int lo = g * B, hi = lo + B;
    int br = blockIdx.x >> 3;
    int nb = gridDim.x >> 3;
    const int4* d4 = (const int4*)dst;
    int E4 = E >> 2;
    for (int i = br * 256 + threadIdx.x; i < E4; i += nb * 256) {
        int4 d = d4[i];
        if (d.x >= lo && d.x < hi) atomicAdd(&deg[d.x], 1);
        if (d.y >= lo && d.y < hi) atomicAdd(&deg[d.y], 1);
        if (d.z >= lo && d.z < hi) atomicAdd(&deg[d.z], 1);
        if (d.w >= lo && d.w < hi) atomicAdd(&deg[d.w], 1);
    }
}

__global__ __launch_bounds__(256) void k_scan1(const int* __restrict__ deg, int* __restrict__ rowptr,
                                               int* __restrict__ bsum, int N) {
    __shared__ int sh[256];
    int i = blockIdx.x * 256 + threadIdx.x;
    int v = (i < N) ? ((deg[i] + 7) & ~7) : 0;
    sh[threadIdx.x] = v;
    for (int off = 1; off < 256; off <<= 1) {
        __syncthreads();
        int t = (threadIdx.x >= off) ? sh[threadIdx.x - off] : 0;
        __syncthreads();
        sh[threadIdx.x] += t;
    }
    __syncthreads();
    if (i <= N) rowptr[i] = sh[threadIdx.x] - v;
    if (threadIdx.x == 255) bsum[blockIdx.x] = sh[255];
}

__global__ __launch_bounds__(512) void k_scan2(int* __restrict__ bsum, int nb) {
    __shared__ int sh[512];
    int v = (threadIdx.x < nb) ? bsum[threadIdx.x] : 0;
    sh[threadIdx.x] = v;
    for (int off = 1; off < 512; off <<= 1) {
        __syncthreads();
        int t = (threadIdx.x >= off) ? sh[threadIdx.x - off] : 0;
        __syncthreads();
        sh[threadIdx.x] += t;
    }
    __syncthreads();
    if (threadIdx.x < nb) bsum[threadIdx.x] = sh[threadIdx.x] - v;
}

__global__ __launch_bounds__(256) void k_scan3(int* __restrict__ rowptr, const int* __restrict__ bsum,
                                               int* __restrict__ cursor, int N) {
    int i = blockIdx.x * 256 + threadIdx.x;
    if (i <= N) {
        int v = rowptr[i] + bsum[i >> 8];
        rowptr[i] = v;
        if (i < N) cursor[i] = v;
    }
}

__global__ __launch_bounds__(256) void k_scatter(const int* __restrict__ src, const int* __restrict__ dst,
                                                 int* __restrict__ cursor, int* __restrict__ ssrc,
                                                 int E, int B) {
    int g = blockIdx.x & 7;
    int lo = g * B, hi = lo + B;
    int br = blockIdx.x >> 3;
    int nb = gridDim.x >> 3;
    const int4* d4 = (const int4*)dst;
    int E4 = E >> 2;
    for (int i = br * 256 + threadIdx.x; i < E4; i += nb * 256) {
        int4 d = d4[i];
        int e = i * 4;
        if (d.x >= lo && d.x < hi) { int pos = atomicAdd(&cursor[d.x], 1); ssrc[pos] = src[e]; }
        if (d.y >= lo && d.y < hi) { int pos = atomicAdd(&cursor[d.y], 1); ssrc[pos] = src[e + 1]; }
        if (d.z >= lo && d.z < hi) { int pos = atomicAdd(&cursor[d.z], 1); ssrc[pos] = src[e + 2]; }
        if (d.w >= lo && d.w < hi) { int pos = atomicAdd(&cursor[d.w], 1); ssrc[pos] = src[e + 3]; }
    }
}

// ---------------- fused GEMM ----------------
// MODE 0: A = x (f32 row-major). MODE 1: A = relu(o*cA+cB), o bf16 col-tiled.
// Out: P_t[g][NP][16] bf16, R_t[g][N][16] bf16 (= X@Wr^T + bl).

template <int MODE>
__global__ __launch_bounds__(256) void k_gemm(const void* __restrict__ srcv, const float* __restrict__ cA,
                                              const float* __restrict__ cB, const bf16* __restrict__ W,
                                              const float* __restrict__ bl, bf16* __restrict__ P,
                                              bf16* __restrict__ R, int Cout, int N, int NP) {
    int wv = blockIdx.x * 4 + (threadIdx.x >> 6);
    int lane = threadIdx.x & 63;
    int node0 = wv * 16;
    if (node0 >= N) return;
    int m = lane & 15, quad = lane >> 4;
    bf16x8 a[4];
    if (MODE == 0) {
        const float* x = (const float*)srcv;
        const float* xr = x + (size_t)(node0 + m) * 128 + quad * 8;
#pragma unroll
        for (int t = 0; t < 4; t++) {
            float4 v0 = *(const float4*)(xr + t * 32);
            float4 v1 = *(const float4*)(xr + t * 32 + 4);
            bf16x8 f = {(bf16)v0.x, (bf16)v0.y, (bf16)v0.z, (bf16)v0.w,
                        (bf16)v1.x, (bf16)v1.y, (bf16)v1.z, (bf16)v1.w};
            a[t] = f;
        }
    } else {
        const bf16* o = (const bf16*)srcv;
#pragma unroll
        for (int t = 0; t < 4; t++) {
            int col0 = t * 32 + quad * 8;
            int g = col0 >> 4;
            int offs = col0 & 15;
            bf16x8 u = *(const bf16x8*)(o + (size_t)g * N * 16 + (size_t)(node0 + m) * 16 + offs);
            float4 ca0 = *(const float4*)(cA + col0);
            float4 ca1 = *(const float4*)(cA + col0 + 4);
            float4 cb0 = *(const float4*)(cB + col0);
            float4 cb1 = *(const float4*)(cB + col0 + 4);
            float h0 = fmaxf(fmaf((float)u[0], ca0.x, cb0.x), 0.f);
            float h1 = fmaxf(fmaf((float)u[1], ca0.y, cb0.y), 0.f);
            float h2 = fmaxf(fmaf((float)u[2], ca0.z, cb0.z), 0.f);
            float h3 = fmaxf(fmaf((float)u[3], ca0.w, cb0.w), 0.f);
            float h4 = fmaxf(fmaf((float)u[4], ca1.x, cb1.x), 0.f);
            float h5 = fmaxf(fmaf((float)u[5], ca1.y, cb1.y), 0.f);
            float h6 = fmaxf(fmaf((float)u[6], ca1.z, cb1.z), 0.f);
            float h7 = fmaxf(fmaf((float)u[7], ca1.w, cb1.w), 0.f);
            bf16x8 f = {(bf16)h0, (bf16)h1, (bf16)h2, (bf16)h3,
                        (bf16)h4, (bf16)h5, (bf16)h6, (bf16)h7};
            a[t] = f;
        }
    }
    int ntiles = (2 * Cout) >> 4;
    int ntilesP = Cout >> 4;
    for (int ct = 0; ct < ntiles; ct++) {
        const bf16* wr = W + (size_t)(ct * 16 + m) * 128 + quad * 8;
        f32x4 acc = {0.f, 0.f, 0.f, 0.f};
        acc = __builtin_amdgcn_mfma_f32_16x16x32_bf16(a[0], *(const bf16x8*)(wr), acc, 0, 0, 0);
        acc = __builtin_amdgcn_mfma_f32_16x16x32_bf16(a[1], *(const bf16x8*)(wr + 32), acc, 0, 0, 0);
        acc = __builtin_amdgcn_mfma_f32_16x16x32_bf16(a[2], *(const bf16x8*)(wr + 64), acc, 0, 0, 0);
        acc = __builtin_amdgcn_mfma_f32_16x16x32_bf16(a[3], *(const bf16x8*)(wr + 96), acc, 0, 0, 0);
        if (ct < ntilesP) {
            bf16* pp = P + (size_t)ct * NP * 16 + (size_t)(node0 + quad * 4) * 16 + m;
            pp[0] = (bf16)acc[0];
            pp[16] = (bf16)acc[1];
            pp[32] = (bf16)acc[2];
            pp[48] = (bf16)acc[3];
        } else {
            int gt = ct - ntilesP;
            float bb = bl[gt * 16 + m];
            bf16* rr = R + (size_t)gt * N * 16 + (size_t)(node0 + quad * 4) * 16 + m;
            rr[0] = (bf16)(acc[0] + bb);
            rr[16] = (bf16)(acc[1] + bb);
            rr[32] = (bf16)(acc[2] + bb);
            rr[48] = (bf16)(acc[3] + bb);
        }
    }
}

// ---------------- aggregate (XCD-sharded, wide gathers) ----------------
// 8 lanes per node; per step 4 edges x 2 lanes x dwordx4 (16B = half of 32B row).
// Idx: 1 dword per lane (2 lanes share an edge). Lane-slots/edge/cg = 4 (was 16).
// deg padded to 8 -> edge loop runs iters = pad/8 full steps of 8 edges.

template <int NG>
__global__ __launch_bounds__(256, 8) void k_agg(const bf16* __restrict__ p, const bf16* __restrict__ r,
                                                const int* __restrict__ rowptr, const int* __restrict__ deg,
                                                const int* __restrict__ ssrc, bf16* __restrict__ o,
                                                float* __restrict__ ssum, float* __restrict__ ssq,
                                                int N, int NP) {
    int g = blockIdx.x & 7;
    int cg = g % NG;
    constexpr int NREP = 8 / NG;
    int rep = g / NG;
    int wvr = ((blockIdx.x >> 3) * NREP + rep) * 4 + (threadIdx.x >> 6);
    int nwv = (gridDim.x >> 3) * NREP * 4;
    int lane = threadIdx.x & 63;
    int sub = lane & 7;
    int grp = lane >> 3;
    int half = sub & 1;   // which 16B half of the 32B row
    int epos = sub >> 1;  // which of 4 edges in a half-step
    const uint4* pu = (const uint4*)(p + (size_t)cg * NP * 16);  // row = 2 x uint4
    const uint4* ru = (const uint4*)(r + (size_t)cg * N * 16);
    bf16* ot = o + (size_t)cg * N * 16;
    float s[8] = {0.f, 0.f, 0.f, 0.f, 0.f, 0.f, 0.f, 0.f};
    float q[8] = {0.f, 0.f, 0.f, 0.f, 0.f, 0.f, 0.f, 0.f};
    int nchunk = (N + 7) >> 3;
    for (int c = wvr; c < nchunk; c += nwv) {
        int n = c * 8 + grp;
        bool valid = n < N;
        int e = 0, iters = 0, d = 1;
        if (valid) {
            e = rowptr[n];
            iters = (rowptr[n + 1] - e) >> 3;
            d = deg[n];
        }
        float a[8] = {0.f, 0.f, 0.f, 0.f, 0.f, 0.f, 0.f, 0.f};
        if (iters > 0) {
            const int* sp = ssrc + e + epos;
            int i0 = sp[0];
            int i1 = sp[4];
            for (int t = 1; t < iters; t++) {
                sp += 8;
                int j0 = sp[0];
                int j1 = sp[4];
                uint4 u = pu[(size_t)i0 * 2 + half];
                uint4 v = pu[(size_t)i1 * 2 + half];
                a[0] += bflo(u.x) + bflo(v.x);
                a[1] += bfhi(u.x) + bfhi(v.x);
                a[2] += bflo(u.y) + bflo(v.y);
                a[3] += bfhi(u.y) + bfhi(v.y);
                a[4] += bflo(u.z) + bflo(v.z);
                a[5] += bfhi(u.z) + bfhi(v.z);
                a[6] += bflo(u.w) + bflo(v.w);
                a[7] += bfhi(u.w) + bfhi(v.w);
                i0 = j0;
                i1 = j1;
            }
            uint4 u = pu[(size_t)i0 * 2 + half];
            uint4 v = pu[(size_t)i1 * 2 + half];
            a[0] += bflo(u.x) + bflo(v.x);
            a[1] += bfhi(u.x) + bfhi(v.x);
            a[2] += bflo(u.y) + bflo(v.y);
            a[3] += bfhi(u.y) + bfhi(v.y);
            a[4] += bflo(u.z) + bflo(v.z);
            a[5] += bfhi(u.z) + bfhi(v.z);
            a[6] += bflo(u.w) + bflo(v.w);
            a[7] += bfhi(u.w) + bfhi(v.w);
        }
        // reduce across the 4 edge-positions (same cols live at same `half`)
#pragma unroll
        for (int msk = 2; msk <= 4; msk <<= 1) {
#pragma unroll
            for (int j = 0; j < 8; j++) a[j] += __shfl_xor(a[j], msk, 64);
        }
        if (valid && epos == 0) {
            float sc = 1.0f / (float)(d > 0 ? d : 1);
            uint4 rv = ru[(size_t)n * 2 + half];
            float o0 = fmaf(a[0], sc, bflo(rv.x));
            float o1 = fmaf(a[1], sc, bfhi(rv.x));
            float o2 = fmaf(a[2], sc, bflo(rv.y));
            float o3 = fmaf(a[3], sc, bfhi(rv.y));
            float o4 = fmaf(a[4], sc, bflo(rv.z));
            float o5 = fmaf(a[5], sc, bfhi(rv.z));
            float o6 = fmaf(a[6], sc, bflo(rv.w));
            float o7 = fmaf(a[7], sc, bfhi(rv.w));
            bf16x8 ov = {(bf16)o0, (bf16)o1, (bf16)o2, (bf16)o3,
                         (bf16)o4, (bf16)o5, (bf16)o6, (bf16)o7};
            *(bf16x8*)(ot + (size_t)n * 16 + half * 8) = ov;
            s[0] += o0; s[1] += o1; s[2] += o2; s[3] += o3;
            s[4] += o4; s[5] += o5; s[6] += o6; s[7] += o7;
            q[0] += o0 * o0; q[1] += o1 * o1; q[2] += o2 * o2; q[3] += o3 * o3;
            q[4] += o4 * o4; q[5] += o5 * o5; q[6] += o6 * o6; q[7] += o7 * o7;
        }
    }
    // stats live in lanes with epos==0 (s/q zero elsewhere); sum across groups
#pragma unroll
    for (int msk = 8; msk < 64; msk <<= 1) {
#pragma unroll
        for (int j = 0; j < 8; j++) {
            s[j] += __shfl_xor(s[j], msk, 64);
            q[j] += __shfl_xor(q[j], msk, 64);
        }
    }
    if (grp == 0 && epos == 0) {
        int c0 = cg * 16 + half * 8;
#pragma unroll
        for (int j = 0; j < 8; j++) {
            atomicAdd(&ssum[c0 + j], s[j]);
            atomicAdd(&ssq[c0 + j], q[j]);
        }
    }
}

// ---------------- BN finalize + final output ----------------

__global__ __launch_bounds__(128) void k_bn_fin(const float* __restrict__ ssum, const float* __restrict__ ssq,
                                                const float* __restrict__ gamma, const float* __restrict__ beta,
                                                float* __restrict__ cA, float* __restrict__ cB, int Cout, int N) {
    int c = threadIdx.x;
    if (c >= Cout) return;
    float m = ssum[c] / (float)N;
    float var = ssq[c] / (float)N - m * m;
    float a = gamma[c] * rsqrtf(var + 1e-5f);
    cA[c] = a;
    cB[c] = beta[c] - m * a;
}

__global__ __launch_bounds__(256) void k_norm_out(const bf16* __restrict__ o, const float* __restrict__ cA,
                                                  const float* __restrict__ cB, float* __restrict__ out, int N) {
    int i = blockIdx.x * 256 + threadIdx.x;
    if (i >= N * 8) return;
    int n = i >> 3;
    int col0 = (i & 7) * 8;
    int g = col0 >> 4;
    int offs = col0 & 15;
    bf16x8 u = *(const bf16x8*)(o + (size_t)g * N * 16 + (size_t)n * 16 + offs);
    float4 ca0 = *(const float4*)(cA + col0);
    float4 ca1 = *(const float4*)(cA + col0 + 4);
    float4 cb0 = *(const float4*)(cB + col0);
    float4 cb1 = *(const float4*)(cB + col0 + 4);
    float4 w0, w1;
    w0.x = fmaf((float)u[0], ca0.x, cb0.x);
    w0.y = fmaf((float)u[1], ca0.y, cb0.y);
    w0.z = fmaf((float)u[2], ca0.z, cb0.z);
    w0.w = fmaf((float)u[3], ca0.w, cb0.w);
    w1.x = fmaf((float)u[4], ca1.x, cb1.x);
    w1.y = fmaf((float)u[5], ca1.y, cb1.y);
    w1.z = fmaf((float)u[6], ca1.z, cb1.z);
    w1.w = fmaf((float)u[7], ca1.w, cb1.w);
    *(float4*)(out + (size_t)n * 64 + col0) = w0;
    *(float4*)(out + (size_t)n * 64 + col0 + 4) = w1;
}

// ---------------- launch ----------------

static inline int cdiv(int a, int b) { return (a + b - 1) / b; }

extern "C" void kernel_launch(void* const* d_in, const int* in_sizes, int n_in,
                              void* d_out, int out_size, void* d_ws, size_t ws_size,
                              hipStream_t stream) {
    const float* x = (const float*)d_in[0];
    const int* ei = (const int*)d_in[1];
    const float* Wl[3] = {(const float*)d_in[2], (const float*)d_in[7], (const float*)d_in[12]};
    const float* bl[3] = {(const float*)d_in[3], (const float*)d_in[8], (const float*)d_in[13]};
    const float* Wr[3] = {(const float*)d_in[4], (const float*)d_in[9], (const float*)d_in[14]};
    const float* gam[3] = {(const float*)d_in[5], (const float*)d_in[10], (const float*)d_in[15]};
    const float* bet[3] = {(const float*)d_in[6], (const float*)d_in[11], (const float*)d_in[16]};

    const int N = in_sizes[0] / 128;  // 100000
    const int E = in_sizes[1] / 2;    // 1600000
    const int NP = N + 8;
    const int Ecap = E + 7 * ((N + 7) & ~7);
    const int B = (N + 7) / 8;
    const int Couts[3] = {128, 128, 64};

    char* base = (char*)d_ws;
    size_t off = 0;
    auto alloc = [&](size_t bytes) -> void* {
        void* ptr = base + off;
        off += (bytes + 255) & ~(size_t)255;
        return ptr;
    };
    bf16* p = (bf16*)alloc((size_t)8 * NP * 16 * 2);
    bf16* r = (bf16*)alloc((size_t)N * 128 * 2);
    bf16* o = (bf16*)alloc((size_t)N * 128 * 2);
    bf16* w0 = (bf16*)alloc(2 * 128 * 128 * 2);
    bf16* w1 = (bf16*)alloc(2 * 128 * 128 * 2);
    bf16* w2 = (bf16*)alloc(2 * 64 * 128 * 2);
    float* stats = (float*)alloc(3 * 512 * 4);
    int* rowptr = (int*)alloc((size_t)(N + 1) * 4);
    int* deg = (int*)alloc((size_t)N * 4);
    int* cursor = (int*)alloc((size_t)N * 4);
    int* bsum = (int*)alloc(512 * 4);
    int* ssrc = (int*)alloc((size_t)Ecap * 4);
    bf16* Wc[3] = {w0, w1, w2};

    const int* esrc = ei;
    const int* edst = ei + E;

    k_init<<<cdiv(Ecap, 256), 256, 0, stream>>>(deg, stats, p, ssrc, N, NP, Ecap);
    k_cvt_w<<<cdiv(128 * 128, 256), 256, 0, stream>>>(Wl[0], Wr[0], w0, 128 * 128);
    k_cvt_w<<<cdiv(128 * 128, 256), 256, 0, stream>>>(Wl[1], Wr[1], w1, 128 * 128);
    k_cvt_w<<<cdiv(64 * 128, 256), 256, 0, stream>>>(Wl[2], Wr[2], w2, 64 * 128);

    k_count<<<2048, 256, 0, stream>>>(edst, deg, E, B);
    int nb = cdiv(N + 1, 256);
    k_scan1<<<nb, 256, 0, stream>>>(deg, rowptr, bsum, N);
    k_scan2<<<1, 512, 0, stream>>>(bsum, nb);
    k_scan3<<<nb, 256, 0, stream>>>(rowptr, bsum, cursor, N);
    k_scatter<<<2048, 256, 0, stream>>>(esrc, edst, cursor, ssrc, E, B);

    const int AGG_BLOCKS = 2048;
    const int GEMM_BLOCKS = cdiv(N, 64);
    for (int l = 0; l < 3; l++) {
        int Cout = Couts[l];
        float* ss = stats + l * 512;
        float* sq = ss + 128;
        float* cA = ss + 256;
        float* cB = ss + 384;
        if (l == 0) {
            k_gemm<0><<<GEMM_BLOCKS, 256, 0, stream>>>(x, nullptr, nullptr, Wc[0], bl[0], p, r, Cout, N, NP);
        } else {
            float* pA = stats + (l - 1) * 512 + 256;
            float* pB = stats + (l - 1) * 512 + 384;
            k_gemm<1><<<GEMM_BLOCKS, 256, 0, stream>>>(o, pA, pB, Wc[l], bl[l], p, r, Cout, N, NP);
        }
        if (Cout == 128) {
            k_agg<8><<<AGG_BLOCKS, 256, 0, stream>>>(p, r, rowptr, deg, ssrc, o, ss, sq, N, NP);
        } else {
            k_agg<4><<<AGG_BLOCKS, 256, 0, stream>>>(p, r, rowptr, deg, ssrc, o, ss, sq, N, NP);
        }
        k_bn_fin<<<1, 128, 0, stream>>>(ss, sq, gam[l], bet[l], cA, cB, Cout, N);
        if (l == 2) {
            k_norm_out<<<cdiv(N * 8, 256), 256, 0, stream>>>(o, cA, cB, (float*)d_out, N);
        }
    }
}

// Round 7
// 765.224 us; speedup vs baseline: 2.0109x; 2.0109x over previous
//
#include <hip/hip_runtime.h>
#include <stdint.h>

typedef __bf16 bf16;
typedef __bf16 bf16x8 __attribute__((ext_vector_type(8)));
typedef __bf16 bf16x4 __attribute__((ext_vector_type(4)));
typedef __bf16 bf16x2 __attribute__((ext_vector_type(2)));
typedef float f32x4 __attribute__((ext_vector_type(4)));

static __device__ __forceinline__ float bflo(uint32_t u) { return __uint_as_float(u << 16); }
static __device__ __forceinline__ float bfhi(uint32_t u) { return __uint_as_float(u & 0xffff0000u); }

// LESSON (R2, R6): scattered dwordx4 gathers run ~4x slower than scattered dword
// gathers per byte on gfx950 (TA charges per dword lane-slot; wide scattered loads
// degrade further). Keep gathers as 1 dword/lane, 8 lanes/row.

// ---------------- init ----------------

__global__ __launch_bounds__(256) void k_init(int* __restrict__ deg, float* __restrict__ stats,
                                              bf16* __restrict__ p, int* __restrict__ ssrc,
                                              int N, int NP, int Ecap) {
    int i = blockIdx.x * 256 + threadIdx.x;
    if (i < N) deg[i] = 0;
    if (i < 3 * 512) stats[i] = 0.f;
    if (i < Ecap) ssrc[i] = N;  // pad -> zero row
    if (i < 128) {
        int g = i >> 4, c = i & 15;
        p[(size_t)g * NP * 16 + (size_t)N * 16 + c] = (bf16)0.f;
    }
}

// one launch for all three layers' weights: [Wl;Wr] -> bf16
__global__ __launch_bounds__(256) void k_cvt_all(const float* __restrict__ wl0, const float* __restrict__ wr0,
                                                 const float* __restrict__ wl1, const float* __restrict__ wr1,
                                                 const float* __restrict__ wl2, const float* __restrict__ wr2,
                                                 bf16* __restrict__ d0, bf16* __restrict__ d1,
                                                 bf16* __restrict__ d2) {
    int i = blockIdx.x * 256 + threadIdx.x;
    if (i < 16384) {
        d0[i] = (bf16)wl0[i];
        d0[16384 + i] = (bf16)wr0[i];
        d1[i] = (bf16)wl1[i];
        d1[16384 + i] = (bf16)wr1[i];
    }
    if (i < 8192) {
        d2[i] = (bf16)wl2[i];
        d2[8192 + i] = (bf16)wr2[i];
    }
}

// ---------------- CSR build (XCD-sharded by dst range) ----------------

__global__ __launch_bounds__(256) void k_count(const int* __restrict__ dst, int* __restrict__ deg,
                                               int E, int B) {
    int g = blockIdx.x & 7;
    int lo = g * B, hi = lo + B;
    int br = blockIdx.x >> 3;
    int nb = gridDim.x >> 3;
    const int4* d4 = (const int4*)dst;
    int E4 = E >> 2;
    for (int i = br * 256 + threadIdx.x; i < E4; i += nb * 256) {
        int4 d = d4[i];
        if (d.x >= lo && d.x < hi) atomicAdd(&deg[d.x], 1);
        if (d.y >= lo && d.y < hi) atomicAdd(&deg[d.y], 1);
        if (d.z >= lo && d.z < hi) atomicAdd(&deg[d.z], 1);
        if (d.w >= lo && d.w < hi) atomicAdd(&deg[d.w], 1);
    }
}

__global__ __launch_bounds__(256) void k_scan1(const int* __restrict__ deg, int* __restrict__ rowptr,
                                               int* __restrict__ bsum, int N) {
    __shared__ int sh[256];
    int i = blockIdx.x * 256 + threadIdx.x;
    int v = (i < N) ? ((deg[i] + 7) & ~7) : 0;
    sh[threadIdx.x] = v;
    for (int off = 1; off < 256; off <<= 1) {
        __syncthreads();
        int t = (threadIdx.x >= off) ? sh[threadIdx.x - off] : 0;
        __syncthreads();
        sh[threadIdx.x] += t;
    }
    __syncthreads();
    if (i <= N) rowptr[i] = sh[threadIdx.x] - v;
    if (threadIdx.x == 255) bsum[blockIdx.x] = sh[255];
}

__global__ __launch_bounds__(512) void k_scan2(int* __restrict__ bsum, int nb) {
    __shared__ int sh[512];
    int v = (threadIdx.x < nb) ? bsum[threadIdx.x] : 0;
    sh[threadIdx.x] = v;
    for (int off = 1; off < 512; off <<= 1) {
        __syncthreads();
        int t = (threadIdx.x >= off) ? sh[threadIdx.x - off] : 0;
        __syncthreads();
        sh[threadIdx.x] += t;
    }
    __syncthreads();
    if (threadIdx.x < nb) bsum[threadIdx.x] = sh[threadIdx.x] - v;
}

__global__ __launch_bounds__(256) void k_scan3(int* __restrict__ rowptr, const int* __restrict__ bsum,
                                               int* __restrict__ cursor, int N) {
    int i = blockIdx.x * 256 + threadIdx.x;
    if (i <= N) {
        int v = rowptr[i] + bsum[i >> 8];
        rowptr[i] = v;
        if (i < N) cursor[i] = v;
    }
}

__global__ __launch_bounds__(256) void k_scatter(const int* __restrict__ src, const int* __restrict__ dst,
                                                 int* __restrict__ cursor, int* __restrict__ ssrc,
                                                 int E, int B) {
    int g = blockIdx.x & 7;
    int lo = g * B, hi = lo + B;
    int br = blockIdx.x >> 3;
    int nb = gridDim.x >> 3;
    const int4* d4 = (const int4*)dst;
    int E4 = E >> 2;
    for (int i = br * 256 + threadIdx.x; i < E4; i += nb * 256) {
        int4 d = d4[i];
        int e = i * 4;
        if (d.x >= lo && d.x < hi) { int pos = atomicAdd(&cursor[d.x], 1); ssrc[pos] = src[e]; }
        if (d.y >= lo && d.y < hi) { int pos = atomicAdd(&cursor[d.y], 1); ssrc[pos] = src[e + 1]; }
        if (d.z >= lo && d.z < hi) { int pos = atomicAdd(&cursor[d.z], 1); ssrc[pos] = src[e + 2]; }
        if (d.w >= lo && d.w < hi) { int pos = atomicAdd(&cursor[d.w], 1); ssrc[pos] = src[e + 3]; }
    }
}

// ---------------- fused GEMM ----------------
// MODE 0: A = x (f32 row-major). MODE 1: A = relu(o*cA+cB), o bf16 col-tiled.
// Out: P_t[g][NP][16] bf16, R_t[g][N][16] bf16 (= X@Wr^T + bl).

template <int MODE>
__global__ __launch_bounds__(256) void k_gemm(const void* __restrict__ srcv, const float* __restrict__ cA,
                                              const float* __restrict__ cB, const bf16* __restrict__ W,
                                              const float* __restrict__ bl, bf16* __restrict__ P,
                                              bf16* __restrict__ R, int Cout, int N, int NP) {
    int wv = blockIdx.x * 4 + (threadIdx.x >> 6);
    int lane = threadIdx.x & 63;
    int node0 = wv * 16;
    if (node0 >= N) return;
    int m = lane & 15, quad = lane >> 4;
    bf16x8 a[4];
    if (MODE == 0) {
        const float* x = (const float*)srcv;
        const float* xr = x + (size_t)(node0 + m) * 128 + quad * 8;
#pragma unroll
        for (int t = 0; t < 4; t++) {
            float4 v0 = *(const float4*)(xr + t * 32);
            float4 v1 = *(const float4*)(xr + t * 32 + 4);
            bf16x8 f = {(bf16)v0.x, (bf16)v0.y, (bf16)v0.z, (bf16)v0.w,
                        (bf16)v1.x, (bf16)v1.y, (bf16)v1.z, (bf16)v1.w};
            a[t] = f;
        }
    } else {
        const bf16* o = (const bf16*)srcv;
#pragma unroll
        for (int t = 0; t < 4; t++) {
            int col0 = t * 32 + quad * 8;
            int g = col0 >> 4;
            int offs = col0 & 15;
            bf16x8 u = *(const bf16x8*)(o + (size_t)g * N * 16 + (size_t)(node0 + m) * 16 + offs);
            float4 ca0 = *(const float4*)(cA + col0);
            float4 ca1 = *(const float4*)(cA + col0 + 4);
            float4 cb0 = *(const float4*)(cB + col0);
            float4 cb1 = *(const float4*)(cB + col0 + 4);
            float h0 = fmaxf(fmaf((float)u[0], ca0.x, cb0.x), 0.f);
            float h1 = fmaxf(fmaf((float)u[1], ca0.y, cb0.y), 0.f);
            float h2 = fmaxf(fmaf((float)u[2], ca0.z, cb0.z), 0.f);
            float h3 = fmaxf(fmaf((float)u[3], ca0.w, cb0.w), 0.f);
            float h4 = fmaxf(fmaf((float)u[4], ca1.x, cb1.x), 0.f);
            float h5 = fmaxf(fmaf((float)u[5], ca1.y, cb1.y), 0.f);
            float h6 = fmaxf(fmaf((float)u[6], ca1.z, cb1.z), 0.f);
            float h7 = fmaxf(fmaf((float)u[7], ca1.w, cb1.w), 0.f);
            bf16x8 f = {(bf16)h0, (bf16)h1, (bf16)h2, (bf16)h3,
                        (bf16)h4, (bf16)h5, (bf16)h6, (bf16)h7};
            a[t] = f;
        }
    }
    int ntiles = (2 * Cout) >> 4;
    int ntilesP = Cout >> 4;
    for (int ct = 0; ct < ntiles; ct++) {
        const bf16* wr = W + (size_t)(ct * 16 + m) * 128 + quad * 8;
        f32x4 acc = {0.f, 0.f, 0.f, 0.f};
        acc = __builtin_amdgcn_mfma_f32_16x16x32_bf16(a[0], *(const bf16x8*)(wr), acc, 0, 0, 0);
        acc = __builtin_amdgcn_mfma_f32_16x16x32_bf16(a[1], *(const bf16x8*)(wr + 32), acc, 0, 0, 0);
        acc = __builtin_amdgcn_mfma_f32_16x16x32_bf16(a[2], *(const bf16x8*)(wr + 64), acc, 0, 0, 0);
        acc = __builtin_amdgcn_mfma_f32_16x16x32_bf16(a[3], *(const bf16x8*)(wr + 96), acc, 0, 0, 0);
        if (ct < ntilesP) {
            bf16* pp = P + (size_t)ct * NP * 16 + (size_t)(node0 + quad * 4) * 16 + m;
            pp[0] = (bf16)acc[0];
            pp[16] = (bf16)acc[1];
            pp[32] = (bf16)acc[2];
            pp[48] = (bf16)acc[3];
        } else {
            int gt = ct - ntilesP;
            float bb = bl[gt * 16 + m];
            bf16* rr = R + (size_t)gt * N * 16 + (size_t)(node0 + quad * 4) * 16 + m;
            rr[0] = (bf16)(acc[0] + bb);
            rr[16] = (bf16)(acc[1] + bb);
            rr[32] = (bf16)(acc[2] + bb);
            rr[48] = (bf16)(acc[3] + bb);
        }
    }
}

// ---------------- aggregate (XCD-sharded, dword gathers, shuffle-broadcast idx) ----------------
// 8-lane group per node; lane owns 2 cols (1 dword of the 32B row). Edge loop 8-deep.
// Index fetch: lane sub loads sp[sub] (1 coalesced instr per 8 edges), broadcast
// within group via __shfl -> idx VMEM slots drop 8x vs per-lane redundant loads.

template <int NG>
__global__ __launch_bounds__(256, 8) void k_agg(const bf16* __restrict__ p, const bf16* __restrict__ r,
                                                const int* __restrict__ rowptr, const int* __restrict__ deg,
                                                const int* __restrict__ ssrc, bf16* __restrict__ o,
                                                float* __restrict__ ssum, float* __restrict__ ssq,
                                                int N, int NP) {
    int g = blockIdx.x & 7;
    int cg = g % NG;
    constexpr int NREP = 8 / NG;
    int rep = g / NG;
    int wvr = ((blockIdx.x >> 3) * NREP + rep) * 4 + (threadIdx.x >> 6);
    int nwv = (gridDim.x >> 3) * NREP * 4;
    int lane = threadIdx.x & 63;
    int sub = lane & 7;
    int grp = lane >> 3;
    int sbase = lane & ~7;  // first lane of this group
    const uint32_t* pu = (const uint32_t*)(p + (size_t)cg * NP * 16);
    const uint32_t* ru = (const uint32_t*)(r + (size_t)cg * N * 16);
    bf16* ot = o + (size_t)cg * N * 16;
    float s0 = 0.f, s1 = 0.f, q0 = 0.f, q1 = 0.f;
    int nchunk = (N + 7) >> 3;
    for (int c = wvr; c < nchunk; c += nwv) {
        int n = c * 8 + grp;
        bool valid = n < N;
        int e = 0, iters = 0, d = 1;
        if (valid) {
            e = rowptr[n];
            iters = (rowptr[n + 1] - e) >> 3;
            d = deg[n];
        }
        float a0 = 0.f, a1 = 0.f;
        auto gather8 = [&](int my) {
            int i0 = __shfl(my, sbase + 0, 64);
            int i1 = __shfl(my, sbase + 1, 64);
            int i2 = __shfl(my, sbase + 2, 64);
            int i3 = __shfl(my, sbase + 3, 64);
            int i4 = __shfl(my, sbase + 4, 64);
            int i5 = __shfl(my, sbase + 5, 64);
            int i6 = __shfl(my, sbase + 6, 64);
            int i7 = __shfl(my, sbase + 7, 64);
            uint32_t u0 = pu[(size_t)i0 * 8 + sub];
            uint32_t u1 = pu[(size_t)i1 * 8 + sub];
            uint32_t u2 = pu[(size_t)i2 * 8 + sub];
            uint32_t u3 = pu[(size_t)i3 * 8 + sub];
            uint32_t u4 = pu[(size_t)i4 * 8 + sub];
            uint32_t u5 = pu[(size_t)i5 * 8 + sub];
            uint32_t u6 = pu[(size_t)i6 * 8 + sub];
            uint32_t u7 = pu[(size_t)i7 * 8 + sub];
            a0 += ((bflo(u0) + bflo(u1)) + (bflo(u2) + bflo(u3))) +
                  ((bflo(u4) + bflo(u5)) + (bflo(u6) + bflo(u7)));
            a1 += ((bfhi(u0) + bfhi(u1)) + (bfhi(u2) + bfhi(u3))) +
                  ((bfhi(u4) + bfhi(u5)) + (bfhi(u6) + bfhi(u7)));
        };
        if (iters > 0) {
            const int* sp = ssrc + e;
            int my = sp[sub];
            for (int t = 1; t < iters; t++) {
                sp += 8;
                int nx = sp[sub];
                gather8(my);
                my = nx;
            }
            gather8(my);
        }
        if (valid) {
            float sc = 1.0f / (float)(d > 0 ? d : 1);
            uint32_t rv = ru[(size_t)n * 8 + sub];
            float o0 = fmaf(a0, sc, bflo(rv));
            float o1 = fmaf(a1, sc, bfhi(rv));
            bf16x2 ov = {(bf16)o0, (bf16)o1};
            *(bf16x2*)(ot + (size_t)n * 16 + sub * 2) = ov;
            s0 += o0;
            s1 += o1;
            q0 += o0 * o0;
            q1 += o1 * o1;
        }
    }
#pragma unroll
    for (int msk = 8; msk < 64; msk <<= 1) {
        s0 += __shfl_xor(s0, msk, 64);
        s1 += __shfl_xor(s1, msk, 64);
        q0 += __shfl_xor(q0, msk, 64);
        q1 += __shfl_xor(q1, msk, 64);
    }
    if (grp == 0) {
        int c = cg * 16 + sub * 2;
        atomicAdd(&ssum[c], s0);
        atomicAdd(&ssum[c + 1], s1);
        atomicAdd(&ssq[c], q0);
        atomicAdd(&ssq[c + 1], q1);
    }
}

// ---------------- BN finalize + final output ----------------

__global__ __launch_bounds__(128) void k_bn_fin(const float* __restrict__ ssum, const float* __restrict__ ssq,
                                                const float* __restrict__ gamma, const float* __restrict__ beta,
                                                float* __restrict__ cA, float* __restrict__ cB, int Cout, int N) {
    int c = threadIdx.x;
    if (c >= Cout) return;
    float m = ssum[c] / (float)N;
    float var = ssq[c] / (float)N - m * m;
    float a = gamma[c] * rsqrtf(var + 1e-5f);
    cA[c] = a;
    cB[c] = beta[c] - m * a;
}

__global__ __launch_bounds__(256) void k_norm_out(const bf16* __restrict__ o, const float* __restrict__ cA,
                                                  const float* __restrict__ cB, float* __restrict__ out, int N) {
    int i = blockIdx.x * 256 + threadIdx.x;
    if (i >= N * 8) return;
    int n = i >> 3;
    int col0 = (i & 7) * 8;
    int g = col0 >> 4;
    int offs = col0 & 15;
    bf16x8 u = *(const bf16x8*)(o + (size_t)g * N * 16 + (size_t)n * 16 + offs);
    float4 ca0 = *(const float4*)(cA + col0);
    float4 ca1 = *(const float4*)(cA + col0 + 4);
    float4 cb0 = *(const float4*)(cB + col0);
    float4 cb1 = *(const float4*)(cB + col0 + 4);
    float4 w0, w1;
    w0.x = fmaf((float)u[0], ca0.x, cb0.x);
    w0.y = fmaf((float)u[1], ca0.y, cb0.y);
    w0.z = fmaf((float)u[2], ca0.z, cb0.z);
    w0.w = fmaf((float)u[3], ca0.w, cb0.w);
    w1.x = fmaf((float)u[4], ca1.x, cb1.x);
    w1.y = fmaf((float)u[5], ca1.y, cb1.y);
    w1.z = fmaf((float)u[6], ca1.z, cb1.z);
    w1.w = fmaf((float)u[7], ca1.w, cb1.w);
    *(float4*)(out + (size_t)n * 64 + col0) = w0;
    *(float4*)(out + (size_t)n * 64 + col0 + 4) = w1;
}

// ---------------- launch ----------------

static inline int cdiv(int a, int b) { return (a + b - 1) / b; }

extern "C" void kernel_launch(void* const* d_in, const int* in_sizes, int n_in,
                              void* d_out, int out_size, void* d_ws, size_t ws_size,
                              hipStream_t stream) {
    const float* x = (const float*)d_in[0];
    const int* ei = (const int*)d_in[1];
    const float* Wl[3] = {(const float*)d_in[2], (const float*)d_in[7], (const float*)d_in[12]};
    const float* bl[3] = {(const float*)d_in[3], (const float*)d_in[8], (const float*)d_in[13]};
    const float* Wr[3] = {(const float*)d_in[4], (const float*)d_in[9], (const float*)d_in[14]};
    const float* gam[3] = {(const float*)d_in[5], (const float*)d_in[10], (const float*)d_in[15]};
    const float* bet[3] = {(const float*)d_in[6], (const float*)d_in[11], (const float*)d_in[16]};

    const int N = in_sizes[0] / 128;  // 100000
    const int E = in_sizes[1] / 2;    // 1600000
    const int NP = N + 8;
    const int Ecap = E + 7 * ((N + 7) & ~7);
    const int B = (N + 7) / 8;
    const int Couts[3] = {128, 128, 64};

    char* base = (char*)d_ws;
    size_t off = 0;
    auto alloc = [&](size_t bytes) -> void* {
        void* ptr = base + off;
        off += (bytes + 255) & ~(size_t)255;
        return ptr;
    };
    bf16* p = (bf16*)alloc((size_t)8 * NP * 16 * 2);
    bf16* r = (bf16*)alloc((size_t)N * 128 * 2);
    bf16* o = (bf16*)alloc((size_t)N * 128 * 2);
    bf16* w0 = (bf16*)alloc(2 * 128 * 128 * 2);
    bf16* w1 = (bf16*)alloc(2 * 128 * 128 * 2);
    bf16* w2 = (bf16*)alloc(2 * 64 * 128 * 2);
    float* stats = (float*)alloc(3 * 512 * 4);
    int* rowptr = (int*)alloc((size_t)(N + 1) * 4);
    int* deg = (int*)alloc((size_t)N * 4);
    int* cursor = (int*)alloc((size_t)N * 4);
    int* bsum = (int*)alloc(512 * 4);
    int* ssrc = (int*)alloc((size_t)Ecap * 4);
    bf16* Wc[3] = {w0, w1, w2};

    const int* esrc = ei;
    const int* edst = ei + E;

    k_init<<<cdiv(Ecap, 256), 256, 0, stream>>>(deg, stats, p, ssrc, N, NP, Ecap);
    k_cvt_all<<<64, 256, 0, stream>>>(Wl[0], Wr[0], Wl[1], Wr[1], Wl[2], Wr[2], w0, w1, w2);

    k_count<<<2048, 256, 0, stream>>>(edst, deg, E, B);
    int nb = cdiv(N + 1, 256);
    k_scan1<<<nb, 256, 0, stream>>>(deg, rowptr, bsum, N);
    k_scan2<<<1, 512, 0, stream>>>(bsum, nb);
    k_scan3<<<nb, 256, 0, stream>>>(rowptr, bsum, cursor, N);
    k_scatter<<<2048, 256, 0, stream>>>(esrc, edst, cursor, ssrc, E, B);

    const int AGG_BLOCKS = 2048;
    const int GEMM_BLOCKS = cdiv(N, 64);
    for (int l = 0; l < 3; l++) {
        int Cout = Couts[l];
        float* ss = stats + l * 512;
        float* sq = ss + 128;
        float* cA = ss + 256;
        float* cB = ss + 384;
        if (l == 0) {
            k_gemm<0><<<GEMM_BLOCKS, 256, 0, stream>>>(x, nullptr, nullptr, Wc[0], bl[0], p, r, Cout, N, NP);
        } else {
            float* pA = stats + (l - 1) * 512 + 256;
            float* pB = stats + (l - 1) * 512 + 384;
            k_gemm<1><<<GEMM_BLOCKS, 256, 0, stream>>>(o, pA, pB, Wc[l], bl[l], p, r, Cout, N, NP);
        }
        if (Cout == 128) {
            k_agg<8><<<AGG_BLOCKS, 256, 0, stream>>>(p, r, rowptr, deg, ssrc, o, ss, sq, N, NP);
        } else {
            k_agg<4><<<AGG_BLOCKS, 256, 0, stream>>>(p, r, rowptr, deg, ssrc, o, ss, sq, N, NP);
        }
        k_bn_fin<<<1, 128, 0, stream>>>(ss, sq, gam[l], bet[l], cA, cB, Cout, N);
        if (l == 2) {
            k_norm_out<<<cdiv(N * 8, 256), 256, 0, stream>>>(o, cA, cB, (float*)d_out, N);
        }
    }
}